// Round 3
// baseline (476.700 us; speedup 1.0000x reference)
//
#include <hip/hip_runtime.h>

#define K 11
#define PAD 5              // K/2
#define TS 32              // output tile (32x32)
#define HT (TS + K - 1)    // 42 = tile + halo
#define TSTR 43            // input tile LDS stride
#define HSTR 33            // h-sum LDS stride

// Fused SSIM: clip -> separable 11x11 depthwise convs (H then V) -> map -> mean
__global__ __launch_bounds__(256) void ssim_kernel(
    const float* __restrict__ img1, const float* __restrict__ img2,
    const float* __restrict__ window, float* __restrict__ acc,
    unsigned int* __restrict__ ticket, float* __restrict__ out,
    float invN, int nblocks, int H, int W, int C)
{
    __shared__ float2 tile[HT][TSTR];   // clipped (x1,x2), zero outside image
    __shared__ float4 hA[HT][HSTR];     // horizontal sums: (s1, s2, s11, s22)
    __shared__ float  hB[HT][HSTR];     // horizontal sums: s12
    __shared__ float  gwin[K];
    __shared__ float  wsum[4];

    const int tid = threadIdx.x;
    const int bz = blockIdx.z;
    const int c = bz % C;

    // separable 1-D kernel: g[i] = sum_j w2d[i][j] (= g[i] since sum(g)=1)
    if (tid < K) {
        const float* w2 = window + c * K * K + tid * K;
        float s = 0.f;
        #pragma unroll
        for (int j = 0; j < K; ++j) s += w2[j];
        gwin[tid] = s;
    }

    const int ox = blockIdx.x * TS, oy = blockIdx.y * TS;
    const size_t base = (size_t)bz * H * W;
    const float eps = 1e-6f, hiv = 1.0f - 1e-6f;

    // stage clipped inputs (with halo); zero padding outside image
    for (int i = tid; i < HT * HT; i += 256) {
        int r = i / HT, cc = i % HT;
        int gy = oy - PAD + r, gx = ox - PAD + cc;
        float a = 0.f, b = 0.f;
        if (gy >= 0 && gy < H && gx >= 0 && gx < W) {
            size_t idx = base + (size_t)gy * W + gx;
            a = fminf(fmaxf(img1[idx], eps), hiv);
            b = fminf(fmaxf(img2[idx], eps), hiv);
        }
        tile[r][cc] = make_float2(a, b);
    }
    __syncthreads();

    float g[K];
    #pragma unroll
    for (int k = 0; k < K; ++k) g[k] = gwin[k];

    // horizontal pass: 42 rows x 32 cols, 4 adjacent cols per thread
    for (int i = tid; i < HT * (TS / 4); i += 256) {   // 336 groups
        int r = i >> 3, c0 = (i & 7) * 4;
        float s1[4] = {0,0,0,0}, s2[4] = {0,0,0,0};
        float s11[4] = {0,0,0,0}, s22[4] = {0,0,0,0}, s12[4] = {0,0,0,0};
        #pragma unroll
        for (int kx = 0; kx < K + 3; ++kx) {           // 14 reads cover 4x11 taps
            float2 x = tile[r][c0 + kx];
            float xx = x.x * x.x, yy = x.y * x.y, xy = x.x * x.y;
            #pragma unroll
            for (int p = 0; p < 4; ++p) {
                int kk = kx - p;
                if (kk >= 0 && kk < K) {
                    float gv = g[kk];
                    s1[p]  += gv * x.x;  s2[p]  += gv * x.y;
                    s11[p] += gv * xx;   s22[p] += gv * yy;  s12[p] += gv * xy;
                }
            }
        }
        #pragma unroll
        for (int p = 0; p < 4; ++p) {
            hA[r][c0 + p] = make_float4(s1[p], s2[p], s11[p], s22[p]);
            hB[r][c0 + p] = s12[p];
        }
    }
    __syncthreads();

    // vertical pass: 4 adjacent rows per thread (col = tid&31, rows r0..r0+3)
    const int col = tid & 31;
    const int r0  = (tid >> 5) * 4;
    float m1[4] = {0,0,0,0}, m2[4] = {0,0,0,0};
    float e11[4] = {0,0,0,0}, e22[4] = {0,0,0,0}, e12[4] = {0,0,0,0};
    #pragma unroll
    for (int ky = 0; ky < K + 3; ++ky) {               // 14 reads cover 4x11 taps
        float4 A  = hA[r0 + ky][col];
        float  Bv = hB[r0 + ky][col];
        #pragma unroll
        for (int p = 0; p < 4; ++p) {
            int kk = ky - p;
            if (kk >= 0 && kk < K) {
                float gv = g[kk];
                m1[p]  += gv * A.x;  m2[p]  += gv * A.y;
                e11[p] += gv * A.z;  e22[p] += gv * A.w;  e12[p] += gv * Bv;
            }
        }
    }

    // ssim map + per-thread sum over 4 pixels
    float vsum = 0.f;
    const float C1 = 1e-4f, C2 = 9e-4f;
    #pragma unroll
    for (int p = 0; p < 4; ++p) {
        float mu11 = m1[p] * m1[p], mu22 = m2[p] * m2[p], mu12 = m1[p] * m2[p];
        float s1q = e11[p] - mu11, s2q = e22[p] - mu22, s12v = e12[p] - mu12;
        float num = (2.f * mu12 + C1) * (2.f * s12v + C2);
        float den = (mu11 + mu22 + C1) * (s1q + s2q + C2);
        vsum += num / den;
    }

    // block reduction: wave shuffle -> LDS -> one atomic; last block finalizes
    #pragma unroll
    for (int off = 32; off > 0; off >>= 1) vsum += __shfl_down(vsum, off, 64);
    if ((tid & 63) == 0) wsum[tid >> 6] = vsum;
    __syncthreads();
    if (tid == 0) {
        float bsum = wsum[0] + wsum[1] + wsum[2] + wsum[3];
        atomicAdd(acc, bsum);
        __threadfence();                      // adds visible before ticket
        unsigned t = atomicAdd(ticket, 1u);
        if (t == (unsigned)(nblocks - 1)) {
            float total = atomicAdd(acc, 0.0f);   // atomic read: all adds done
            out[0] = 1.0f - total * invN;
        }
    }
}

extern "C" void kernel_launch(void* const* d_in, const int* in_sizes, int n_in,
                              void* d_out, int out_size, void* d_ws, size_t ws_size,
                              hipStream_t stream) {
    const float* img1 = (const float*)d_in[0];
    const float* img2 = (const float*)d_in[1];
    const float* window = (const float*)d_in[2];
    float* out = (float*)d_out;
    float* acc = (float*)d_ws;
    unsigned int* ticket = (unsigned int*)((char*)d_ws + sizeof(float));

    const int B = 16, C = 3, H = 512, W = 512;
    const float invN = 1.0f / ((float)B * C * H * W);

    // d_ws poisoned 0xAA before every call: zero acc + ticket (8 bytes)
    hipMemsetAsync(d_ws, 0, 2 * sizeof(float), stream);

    dim3 block(256);
    dim3 grid(W / TS, H / TS, B * C);
    const int nblocks = grid.x * grid.y * grid.z;
    ssim_kernel<<<grid, block, 0, stream>>>(img1, img2, window, acc, ticket,
                                            out, invN, nblocks, H, W, C);
}

// Round 4
// 280.155 us; speedup vs baseline: 1.7016x; 1.7016x over previous
//
#include <hip/hip_runtime.h>

#define K 11
#define PAD 5              // K/2
#define TS 32              // output tile (32x32)
#define HT (TS + K - 1)    // 42 = tile + halo
#define TSTR 43            // input tile stride (float2): stride-2 banks, free
#define VSTR 35            // v-sum stride: 35*16B -> 12-step start banks, 2-way

// Fused SSIM: clip -> separable 11x11 depthwise convs (V then H) -> map -> sum
__global__ __launch_bounds__(256) void ssim_kernel(
    const float* __restrict__ img1, const float* __restrict__ img2,
    const float* __restrict__ window, float* __restrict__ acc,
    int H, int W, int C)
{
    __shared__ float2 tile[HT][TSTR];   // clipped (x1,x2), zero outside image
    __shared__ float4 vA[TS][VSTR];     // vertical sums: (s1, s2, s11, s22)
    __shared__ float  vB[TS][VSTR];     // vertical sums: s12
    __shared__ float  gwin[K];
    __shared__ float  wsum[4];

    const int tid = threadIdx.x;
    const int bz = blockIdx.z;
    const int c = bz % C;

    // separable 1-D kernel: g[i] = sum_j w2d[i][j] (= g[i] since sum(g)=1)
    if (tid < K) {
        const float* w2 = window + c * K * K + tid * K;
        float s = 0.f;
        #pragma unroll
        for (int j = 0; j < K; ++j) s += w2[j];
        gwin[tid] = s;
    }

    const int ox = blockIdx.x * TS, oy = blockIdx.y * TS;
    const size_t base = (size_t)bz * H * W;
    const float eps = 1e-6f, hiv = 1.0f - 1e-6f;

    // stage clipped inputs (with halo); zero padding outside image
    for (int i = tid; i < HT * HT; i += 256) {
        int r = i / HT, cc = i % HT;
        int gy = oy - PAD + r, gx = ox - PAD + cc;
        float a = 0.f, b = 0.f;
        if (gy >= 0 && gy < H && gx >= 0 && gx < W) {
            size_t idx = base + (size_t)gy * W + gx;
            a = fminf(fmaxf(img1[idx], eps), hiv);
            b = fminf(fmaxf(img2[idx], eps), hiv);
        }
        tile[r][cc] = make_float2(a, b);
    }
    __syncthreads();

    float g[K];
    #pragma unroll
    for (int k = 0; k < K; ++k) g[k] = gwin[k];

    // vertical pass, register-blocked x4 along y:
    // consecutive lanes -> consecutive columns (R2's conflict-free pattern),
    // each thread computes 4 adjacent output rows sharing 14 tile reads.
    for (int i = tid; i < (TS / 4) * HT; i += 256) {   // 336 groups
        int cc = i % HT;
        int r0 = (i / HT) * 4;
        float s1[4]  = {0,0,0,0}, s2[4]  = {0,0,0,0};
        float s11[4] = {0,0,0,0}, s22[4] = {0,0,0,0}, s12[4] = {0,0,0,0};
        #pragma unroll
        for (int ky = 0; ky < K + 3; ++ky) {           // 14 reads cover 4x11 taps
            float2 x = tile[r0 + ky][cc];
            float xx = x.x * x.x, yy = x.y * x.y, xy = x.x * x.y;
            #pragma unroll
            for (int p = 0; p < 4; ++p) {
                int kk = ky - p;                       // statically resolved
                if (kk >= 0 && kk < K) {
                    float gv = g[kk];
                    s1[p]  += gv * x.x;  s2[p]  += gv * x.y;
                    s11[p] += gv * xx;   s22[p] += gv * yy;  s12[p] += gv * xy;
                }
            }
        }
        #pragma unroll
        for (int p = 0; p < 4; ++p) {                  // lane-sequential stores
            vA[r0 + p][cc] = make_float4(s1[p], s2[p], s11[p], s22[p]);
            vB[r0 + p][cc] = s12[p];
        }
    }
    __syncthreads();

    // horizontal pass (identical to R2): 4 adjacent pixels per thread
    const int row = tid >> 3;          // 0..31
    const int cx  = (tid & 7) * 4;     // 0,4,...,28
    float m1[4]  = {0,0,0,0}, m2[4]  = {0,0,0,0};
    float e11[4] = {0,0,0,0}, e22[4] = {0,0,0,0}, e12[4] = {0,0,0,0};
    #pragma unroll
    for (int kx = 0; kx < K + 3; ++kx) {               // 14 reads cover 4x11 taps
        float4 A  = vA[row][cx + kx];
        float  Bv = vB[row][cx + kx];
        #pragma unroll
        for (int p = 0; p < 4; ++p) {
            int kk = kx - p;
            if (kk >= 0 && kk < K) {
                float gv = g[kk];
                m1[p]  += gv * A.x;  m2[p]  += gv * A.y;
                e11[p] += gv * A.z;  e22[p] += gv * A.w;  e12[p] += gv * Bv;
            }
        }
    }

    // ssim map + per-thread sum over 4 pixels
    float vsum = 0.f;
    const float C1 = 1e-4f, C2 = 9e-4f;
    #pragma unroll
    for (int p = 0; p < 4; ++p) {
        float mu11 = m1[p] * m1[p], mu22 = m2[p] * m2[p], mu12 = m1[p] * m2[p];
        float s1q = e11[p] - mu11, s2q = e22[p] - mu22, s12v = e12[p] - mu12;
        float num = (2.f * mu12 + C1) * (2.f * s12v + C2);
        float den = (mu11 + mu22 + C1) * (s1q + s2q + C2);
        vsum += num / den;
    }

    // block reduction: wave shuffle -> LDS -> one fire-and-forget atomic
    #pragma unroll
    for (int off = 32; off > 0; off >>= 1) vsum += __shfl_down(vsum, off, 64);
    if ((tid & 63) == 0) wsum[tid >> 6] = vsum;
    __syncthreads();
    if (tid == 0) {
        atomicAdd(acc, wsum[0] + wsum[1] + wsum[2] + wsum[3]);
    }
}

__global__ void ssim_finalize(const float* __restrict__ acc,
                              float* __restrict__ out, float invN)
{
    out[0] = 1.0f - acc[0] * invN;
}

extern "C" void kernel_launch(void* const* d_in, const int* in_sizes, int n_in,
                              void* d_out, int out_size, void* d_ws, size_t ws_size,
                              hipStream_t stream) {
    const float* img1 = (const float*)d_in[0];
    const float* img2 = (const float*)d_in[1];
    const float* window = (const float*)d_in[2];
    float* out = (float*)d_out;
    float* acc = (float*)d_ws;

    const int B = 16, C = 3, H = 512, W = 512;
    const float invN = 1.0f / ((float)B * C * H * W);

    // d_ws is poisoned (0xAA) before every call: zero the accumulator
    hipMemsetAsync(acc, 0, sizeof(float), stream);

    dim3 block(256);
    dim3 grid(W / TS, H / TS, B * C);
    ssim_kernel<<<grid, block, 0, stream>>>(img1, img2, window, acc, H, W, C);
    ssim_finalize<<<1, 1, 0, stream>>>(acc, out, invN);
}

// Round 6
// 192.152 us; speedup vs baseline: 2.4809x; 1.4580x over previous
//
#include <hip/hip_runtime.h>

typedef _Float16 f16;
typedef _Float16 half8 __attribute__((ext_vector_type(8)));
typedef float floatx16 __attribute__((ext_vector_type(16)));

#define KW 11
#define TILE_C 112          // valid output cols per block
#define TILE_R 32           // output rows per block
#define XC 128              // staged cols (ti = 0..127), ti -> global col cx0-5+ti
#define XSTR 48             // bytes per staged col per field (16 f16 rows, padded 32->48)
#define TSTR 168            // T col-stride in f16 elems (336B row: 16B-aligned)
#define T_FSZ (TILE_R * TSTR)      // per-field T elems
#define X_FSZ (XC * XSTR)          // per-field X bytes (6144)
#define T_BYTES (4 * T_FSZ * 2)    // 43008

// Fused SSIM via MFMA: clip -> 4 fp16 field planes -> banded-matmul separable
// conv (V then H) on matrix cores -> ssim map -> sum
__global__ __launch_bounds__(256, 3) void ssim_kernel(
    const float* __restrict__ img1, const float* __restrict__ img2,
    const float* __restrict__ window, float* __restrict__ acc)
{
    __shared__ __align__(16) char smem[T_BYTES + 192 + 32];
    f16*   T    = (f16*)smem;                 // [4][32][TSTR], written after X dead
    char*  Xb   = smem;                       // union: [4][XC][XSTR bytes]
    f16*   gpad = (f16*)(smem + T_BYTES);     // 96 entries, g at [32..42]
    float* wsum = (float*)(smem + T_BYTES + 192);

    const int tid  = threadIdx.x;
    const int lane = tid & 63;
    const int wv   = tid >> 6;        // wave 0..3 -> out col block 32*wv
    const int q    = lane >> 5;       // lane half
    const int ln   = lane & 31;

    const int bz  = blockIdx.z;
    const int c   = bz % 3;
    const int cx0 = blockIdx.x * TILE_C;
    const int oy  = blockIdx.y * TILE_R;
    const size_t base = (size_t)bz * 512 * 512;

    // zero-padded 1-D gaussian in fp16: gpad[32+i] = g[i] = sum_j w2d[i][j]
    if (tid < 96) {
        float v = 0.f;
        if (tid >= 32 && tid < 32 + KW) {
            const float* w2 = window + c * KW * KW + (tid - 32) * KW;
            #pragma unroll
            for (int j = 0; j < KW; ++j) v += w2[j];
        }
        gpad[tid] = (f16)v;
    }
    __syncthreads();

    // band fragments: value = g[k_abs - m]; identical for Gv-as-A and Gh-as-B.
    // A layout: A[m=ln][k = 8*q + j]; k_abs = 16*ch + 8*q + j.
    half8 band[3];
    #pragma unroll
    for (int ch = 0; ch < 3; ++ch) {
        int d0 = 16 * ch + 8 * q - ln + 32;
        #pragma unroll
        for (int j = 0; j < 8; ++j) band[ch][j] = gpad[d0 + j];
    }

    // ---- vertical pass: T[r][ti] = sum_ri g[ri-r] * X[ri][ti], K=48 chunked ----
    const int ti = tid & 127;          // staged col
    const int rh = tid >> 7;           // row half (0: rows 0-7, 1: rows 8-15)
    const int gx = cx0 - 5 + ti;
    const bool xok = (gx >= 0 && gx < 512);
    char* xcol = Xb + ti * XSTR + rh * 16;
    const float eps = 1e-6f, hiv = 1.0f - 1e-6f;

    floatx16 accT[4] = {};
    #pragma unroll
    for (int ch = 0; ch < 3; ++ch) {
        // stage 16 rows x 128 cols of 4 fp16 field planes (col-major, b128 writes)
        int gy0 = oy - 5 + 16 * ch + rh * 8;
        half8 f0h, f1h, f2h, f3h;
        #pragma unroll
        for (int rr = 0; rr < 8; ++rr) {
            int gy = gy0 + rr;
            float a = 0.f, b = 0.f;
            if (xok && gy >= 0 && gy < 512) {
                size_t idx = base + (size_t)gy * 512 + gx;
                a = fminf(fmaxf(img1[idx], eps), hiv);
                b = fminf(fmaxf(img2[idx], eps), hiv);
            }
            f0h[rr] = (f16)a;
            f1h[rr] = (f16)b;
            f2h[rr] = (f16)(a * a + b * b);
            f3h[rr] = (f16)(a * b);
        }
        *(half8*)(xcol + 0 * X_FSZ) = f0h;
        *(half8*)(xcol + 1 * X_FSZ) = f1h;
        *(half8*)(xcol + 2 * X_FSZ) = f2h;
        *(half8*)(xcol + 3 * X_FSZ) = f3h;
        __syncthreads();

        // B frag: B[k = 8q+j][n = ln] = X[row 8q+j][ti = 32*wv + ln]
        const char* xb = Xb + (32 * wv + ln) * XSTR + q * 16;
        #pragma unroll
        for (int f = 0; f < 4; ++f) {
            half8 bfrag = *(const half8*)(xb + f * X_FSZ);
            accT[f] = __builtin_amdgcn_mfma_f32_32x32x16_f16(band[ch], bfrag, accT[f], 0, 0, 0);
        }
        __syncthreads();   // X reads done before next-chunk overwrite / T write
    }

    // write T (fp16) from C/D layout: row=(r&3)+8*(r>>2)+4*q, col ti=32*wv+ln
    {
        const int tcol = 32 * wv + ln;
        #pragma unroll
        for (int f = 0; f < 4; ++f) {
            #pragma unroll
            for (int r = 0; r < 16; ++r) {
                int row = (r & 3) + 8 * (r >> 2) + 4 * q;
                T[f * T_FSZ + row * TSTR + tcol] = (f16)accT[f][r];
            }
        }
    }
    // zero T cols 128..143: horizontal A-frags read up to col 143; those taps
    // have zero band weight but 0 * garbage(inf/NaN) = NaN.  256 half8 stores.
    {
        int f = tid >> 6, row = (tid >> 1) & 31, seg = tid & 1;
        *(half8*)(T + f * T_FSZ + row * TSTR + 128 + seg * 8) = (half8)(f16)0.f;
    }
    __syncthreads();

    // ---- horizontal pass: OUT[r][32*wv+n] = sum_k g[k] T[r][32*wv+n+k] ----
    floatx16 accH[4] = {};
    #pragma unroll
    for (int ch = 0; ch < 3; ++ch) {
        // A frag: A[m=ln][k=8q+j] = T[row ln][col 32*wv + 16*ch + 8*q + j]
        const f16* tb = T + ln * TSTR + (32 * wv + 16 * ch + 8 * q);
        #pragma unroll
        for (int f = 0; f < 4; ++f) {
            half8 afrag = *(const half8*)(tb + f * T_FSZ);
            accH[f] = __builtin_amdgcn_mfma_f32_32x32x16_f16(afrag, band[ch], accH[f], 0, 0, 0);
        }
    }

    // ---- epilogue: ssim map + sum (cols masked to valid range) ----
    float vsum = 0.f;
    const int colL = 32 * wv + ln;
    if (colL < TILE_C && cx0 + colL < 512) {
        const float C1 = 1e-4f, C2 = 9e-4f;
        #pragma unroll
        for (int r = 0; r < 16; ++r) {
            float mu1 = accH[0][r], mu2 = accH[1][r];
            float S = accH[2][r], E12 = accH[3][r];
            float mu11 = mu1 * mu1, mu22 = mu2 * mu2, mu12 = mu1 * mu2;
            float num = (2.f * mu12 + C1) * (2.f * (E12 - mu12) + C2);
            float den = (mu11 + mu22 + C1) * (S - mu11 - mu22 + C2);
            vsum += num / den;
        }
    }

    // block reduction: wave shuffle -> LDS -> one fire-and-forget atomic
    #pragma unroll
    for (int off = 32; off > 0; off >>= 1) vsum += __shfl_down(vsum, off, 64);
    if ((tid & 63) == 0) wsum[tid >> 6] = vsum;
    __syncthreads();
    if (tid == 0) {
        atomicAdd(acc, wsum[0] + wsum[1] + wsum[2] + wsum[3]);
    }
}

__global__ void ssim_finalize(const float* __restrict__ acc,
                              float* __restrict__ out, float invN)
{
    out[0] = 1.0f - acc[0] * invN;
}

extern "C" void kernel_launch(void* const* d_in, const int* in_sizes, int n_in,
                              void* d_out, int out_size, void* d_ws, size_t ws_size,
                              hipStream_t stream) {
    const float* img1 = (const float*)d_in[0];
    const float* img2 = (const float*)d_in[1];
    const float* window = (const float*)d_in[2];
    float* out = (float*)d_out;
    float* acc = (float*)d_ws;

    const int B = 16, C = 3, H = 512, W = 512;
    const float invN = 1.0f / ((float)B * C * H * W);

    // d_ws is poisoned (0xAA) before every call: zero the accumulator
    hipMemsetAsync(acc, 0, sizeof(float), stream);

    dim3 block(256);
    dim3 grid((W + TILE_C - 1) / TILE_C, H / TILE_R, B * C);   // 5 x 16 x 48
    ssim_kernel<<<grid, block, 0, stream>>>(img1, img2, window, acc);
    ssim_finalize<<<1, 1, 0, stream>>>(acc, out, invN);
}

// Round 7
// 185.678 us; speedup vs baseline: 2.5673x; 1.0349x over previous
//
#include <hip/hip_runtime.h>

typedef _Float16 f16;
typedef _Float16 half8 __attribute__((ext_vector_type(8)));
typedef float floatx16 __attribute__((ext_vector_type(16)));

#define KW 11
#define TILE_C 112          // valid output cols per block
#define TILE_R 32           // output rows per block
#define XC 128              // staged cols (ti = 0..127), ti -> global col cx0-5+ti
#define XSTR 48             // bytes per staged col per field (16 f16 rows, pad 32->48)
#define TSTR 152            // T col-stride in f16 (304B row: 12-step banks, 2-way)
#define T_FSZ (TILE_R * TSTR)      // per-field T elems
#define X_FSZ (XC * XSTR)          // per-field X bytes (6144)
#define T_BYTES (4 * T_FSZ * 2)    // 38912

// Fused SSIM via MFMA: clip -> 4 fp16 field planes -> banded-matmul separable
// conv (V then H) on matrix cores -> ssim map -> sum
__global__ __launch_bounds__(256, 4) void ssim_kernel(
    const float* __restrict__ img1, const float* __restrict__ img2,
    const float* __restrict__ window, float* __restrict__ acc)
{
    __shared__ __align__(16) char smem[T_BYTES + 192 + 32];
    f16*   T    = (f16*)smem;                 // [4][32][TSTR], written after X dead
    char*  Xb   = smem;                       // union: [4][XC][XSTR bytes]
    f16*   gpad = (f16*)(smem + T_BYTES);     // 96 entries, g at [32..42]
    float* wsum = (float*)(smem + T_BYTES + 192);

    const int tid  = threadIdx.x;
    const int lane = tid & 63;
    const int wv   = tid >> 6;        // wave 0..3 -> out col block 32*wv
    const int q    = lane >> 5;       // lane half
    const int ln   = lane & 31;

    const int bz  = blockIdx.z;
    const int c   = bz % 3;
    const int cx0 = blockIdx.x * TILE_C;
    const int oy  = blockIdx.y * TILE_R;
    const size_t base = (size_t)bz * 512 * 512;

    // ---- prefetch ALL 48 rows (3 chunks x 8) of both images to registers ----
    // all coalesced dword loads issue before any barrier phase: one HBM latency
    const int ti = tid & 127;          // staged col
    const int rh = tid >> 7;           // row half (0: rows 0-7, 1: rows 8-15)
    const int gx = cx0 - 5 + ti;
    const bool xok = (gx >= 0 && gx < 512);
    float pa[3][8], pb[3][8];
    #pragma unroll
    for (int ch = 0; ch < 3; ++ch) {
        int gy0 = oy - 5 + 16 * ch + rh * 8;
        #pragma unroll
        for (int rr = 0; rr < 8; ++rr) {
            int gy = gy0 + rr;
            bool ok = xok && gy >= 0 && gy < 512;
            size_t idx = base + (size_t)gy * 512 + gx;
            pa[ch][rr] = ok ? img1[idx] : 0.f;
            pb[ch][rr] = ok ? img2[idx] : 0.f;
        }
    }

    // zero-padded 1-D gaussian in fp16: gpad[32+i] = g[i] = sum_j w2d[i][j]
    if (tid < 96) {
        float v = 0.f;
        if (tid >= 32 && tid < 32 + KW) {
            const float* w2 = window + c * KW * KW + (tid - 32) * KW;
            #pragma unroll
            for (int j = 0; j < KW; ++j) v += w2[j];
        }
        gpad[tid] = (f16)v;
    }
    __syncthreads();

    // band fragments: value = g[k_abs - m]; identical for Gv-as-A and Gh-as-B.
    // A layout: A[m=ln][k = 8*q + j]; k_abs = 16*ch + 8*q + j.
    half8 band[3];
    #pragma unroll
    for (int ch = 0; ch < 3; ++ch) {
        int d0 = 16 * ch + 8 * q - ln + 32;
        #pragma unroll
        for (int j = 0; j < 8; ++j) band[ch][j] = gpad[d0 + j];
    }

    // ---- vertical pass: T[r][ti] = sum_ri g[ri-r] * X[ri][ti], K=48 chunked ----
    char* xcol = Xb + ti * XSTR + rh * 16;
    const float eps = 1e-6f, hiv = 1.0f - 1e-6f;

    floatx16 accT[4] = {};
    #pragma unroll
    for (int ch = 0; ch < 3; ++ch) {
        // convert prefetched rows -> 4 fp16 field planes (col-major, b128 writes)
        half8 f0h, f1h, f2h, f3h;
        #pragma unroll
        for (int rr = 0; rr < 8; ++rr) {
            float a = fminf(fmaxf(pa[ch][rr], eps), hiv);
            float b = fminf(fmaxf(pb[ch][rr], eps), hiv);
            if (!xok) { a = 0.f; b = 0.f; }   // (already 0 from masked load)
            f0h[rr] = (f16)a;
            f1h[rr] = (f16)b;
            f2h[rr] = (f16)(a * a + b * b);
            f3h[rr] = (f16)(a * b);
        }
        *(half8*)(xcol + 0 * X_FSZ) = f0h;
        *(half8*)(xcol + 1 * X_FSZ) = f1h;
        *(half8*)(xcol + 2 * X_FSZ) = f2h;
        *(half8*)(xcol + 3 * X_FSZ) = f3h;
        __syncthreads();

        // B frag: B[k = 8q+j][n = ln] = X[row 8q+j][ti = 32*wv + ln]
        const char* xb = Xb + (32 * wv + ln) * XSTR + q * 16;
        #pragma unroll
        for (int f = 0; f < 4; ++f) {
            half8 bfrag = *(const half8*)(xb + f * X_FSZ);
            accT[f] = __builtin_amdgcn_mfma_f32_32x32x16_f16(band[ch], bfrag, accT[f], 0, 0, 0);
        }
        __syncthreads();   // X reads done before next-chunk overwrite / T write
    }

    // write T (fp16) from C/D layout: row=(r&3)+8*(r>>2)+4*q, col ti=32*wv+ln
    {
        const int tcol = 32 * wv + ln;
        #pragma unroll
        for (int f = 0; f < 4; ++f) {
            #pragma unroll
            for (int r = 0; r < 16; ++r) {
                int row = (r & 3) + 8 * (r >> 2) + 4 * q;
                T[f * T_FSZ + row * TSTR + tcol] = (f16)accT[f][r];
            }
        }
    }
    // zero T cols 128..143: horizontal A-frags read up to col 143; those taps
    // have zero band weight but 0 * garbage(inf/NaN) = NaN.  256 half8 stores.
    {
        int f = tid >> 6, row = (tid >> 1) & 31, seg = tid & 1;
        *(half8*)(T + f * T_FSZ + row * TSTR + 128 + seg * 8) = (half8)(f16)0.f;
    }
    __syncthreads();

    // ---- horizontal pass: OUT[r][32*wv+n] = sum_k g[k] T[r][32*wv+n+k] ----
    floatx16 accH[4] = {};
    #pragma unroll
    for (int ch = 0; ch < 3; ++ch) {
        // A frag: A[m=ln][k=8q+j] = T[row ln][col 32*wv + 16*ch + 8*q + j]
        const f16* tb = T + ln * TSTR + (32 * wv + 16 * ch + 8 * q);
        #pragma unroll
        for (int f = 0; f < 4; ++f) {
            half8 afrag = *(const half8*)(tb + f * T_FSZ);
            accH[f] = __builtin_amdgcn_mfma_f32_32x32x16_f16(afrag, band[ch], accH[f], 0, 0, 0);
        }
    }

    // ---- epilogue: ssim map + sum (cols masked to valid range) ----
    float vsum = 0.f;
    const int colL = 32 * wv + ln;
    if (colL < TILE_C && cx0 + colL < 512) {
        const float C1 = 1e-4f, C2 = 9e-4f;
        #pragma unroll
        for (int r = 0; r < 16; ++r) {
            float mu1 = accH[0][r], mu2 = accH[1][r];
            float S = accH[2][r], E12 = accH[3][r];
            float mu11 = mu1 * mu1, mu22 = mu2 * mu2, mu12 = mu1 * mu2;
            float num = (2.f * mu12 + C1) * (2.f * (E12 - mu12) + C2);
            float den = (mu11 + mu22 + C1) * (S - mu11 - mu22 + C2);
            vsum += num * __builtin_amdgcn_rcpf(den);   // 1-ulp rcp, den>=C1*C2
        }
    }

    // block reduction: wave shuffle -> LDS -> one fire-and-forget atomic
    #pragma unroll
    for (int off = 32; off > 0; off >>= 1) vsum += __shfl_down(vsum, off, 64);
    if ((tid & 63) == 0) wsum[tid >> 6] = vsum;
    __syncthreads();
    if (tid == 0) {
        atomicAdd(acc, wsum[0] + wsum[1] + wsum[2] + wsum[3]);
    }
}

__global__ void ssim_finalize(const float* __restrict__ acc,
                              float* __restrict__ out, float invN)
{
    out[0] = 1.0f - acc[0] * invN;
}

extern "C" void kernel_launch(void* const* d_in, const int* in_sizes, int n_in,
                              void* d_out, int out_size, void* d_ws, size_t ws_size,
                              hipStream_t stream) {
    const float* img1 = (const float*)d_in[0];
    const float* img2 = (const float*)d_in[1];
    const float* window = (const float*)d_in[2];
    float* out = (float*)d_out;
    float* acc = (float*)d_ws;

    const int B = 16, C = 3, H = 512, W = 512;
    const float invN = 1.0f / ((float)B * C * H * W);

    // d_ws is poisoned (0xAA) before every call: zero the accumulator
    hipMemsetAsync(acc, 0, sizeof(float), stream);

    dim3 block(256);
    dim3 grid((W + TILE_C - 1) / TILE_C, H / TILE_R, B * C);   // 5 x 16 x 48
    ssim_kernel<<<grid, block, 0, stream>>>(img1, img2, window, acc);
    ssim_finalize<<<1, 1, 0, stream>>>(acc, out, invN);
}

// Round 9
// 179.533 us; speedup vs baseline: 2.6552x; 1.0342x over previous
//
#include <hip/hip_runtime.h>

typedef _Float16 f16;
typedef __fp16 fp16x2 __attribute__((ext_vector_type(2)));
typedef _Float16 half4 __attribute__((ext_vector_type(4)));
typedef _Float16 half8 __attribute__((ext_vector_type(8)));
typedef float floatx16 __attribute__((ext_vector_type(16)));

#define KW 11
#define TILE_C 112          // valid output cols per block
#define TILE_R 32           // output rows per block
#define TSTR 152            // T col-stride in f16 (304B row; holds cols 0..143)
#define T_FSZ (TILE_R * TSTR)      // per-field T elems
#define T_BYTES (4 * T_FSZ * 2)    // 38912

union H8 { half8 v; fp16x2 p[4]; };
union H4 { half4 v; fp16x2 p[2]; };

// Fused SSIM via MFMA: V-pass computes T^T = X^T * Gv^T with image fragments
// loaded DIRECTLY from global (no X staging, no V-pass barriers), T round-trip
// through LDS (the layout transpose), H-pass = T * Gh^T, ssim map, sum.
__global__ __launch_bounds__(256, 4) void ssim_kernel(
    const float* __restrict__ img1, const float* __restrict__ img2,
    const float* __restrict__ window, float* __restrict__ acc)
{
    __shared__ __align__(16) char smem[T_BYTES + 192 + 32];
    f16*   T    = (f16*)smem;                 // [4 fields][32 rows][TSTR cols]
    f16*   gpad = (f16*)(smem + T_BYTES);     // 96 entries, g at [32..42]
    float* wsum = (float*)(smem + T_BYTES + 192);

    const int tid  = threadIdx.x;
    const int lane = tid & 63;
    const int wv   = tid >> 6;        // wave 0..3 -> col block 32*wv
    const int q    = lane >> 5;       // lane half
    const int ln   = lane & 31;

    const int bz  = blockIdx.z;
    const int c   = bz % 3;
    const int cx0 = blockIdx.x * TILE_C;
    const int oy  = blockIdx.y * TILE_R;
    const size_t base = (size_t)bz * 512 * 512;

    // zero-padded 1-D gaussian in fp16: gpad[32+i] = g[i] = sum_j w2d[i][j]
    if (tid < 96) {
        float v = 0.f;
        if (tid >= 32 && tid < 32 + KW) {
            const float* w2 = window + c * KW * KW + (tid - 32) * KW;
            #pragma unroll
            for (int j = 0; j < KW; ++j) v += w2[j];
        }
        gpad[tid] = (f16)v;
    }
    __syncthreads();

    // band fragments B[k=8q+j][n=ln] = g[k_abs - n]; serves BOTH passes
    // (Gv^T in V-pass, Gh in H-pass) -- same banded structure.
    half8 band[3];
    #pragma unroll
    for (int ch = 0; ch < 3; ++ch) {
        int d0 = 16 * ch + 8 * q - ln + 32;
        #pragma unroll
        for (int j = 0; j < 8; ++j) band[ch][j] = gpad[d0 + j];
    }

    // ---- V-pass: T^T = X^T * Gv^T.  A-frag = 8 consecutive image rows of
    // this lane's column, loaded straight from global (coalesced dwords). ----
    const int gx = cx0 - 5 + 32 * wv + ln;    // this lane's pixel column
    const bool xok = (gx >= 0 && gx < 512);
    const float* p1 = img1 + base + gx;
    const float* p2 = img2 + base + gx;
    const float eps = 1e-6f, hiv = 1.0f - 1e-6f;

    floatx16 accT[4] = {};
    #pragma unroll
    for (int ch = 0; ch < 3; ++ch) {
        const int gy0 = oy - 5 + 16 * ch + 8 * q;
        float av[8], bv[8];
        #pragma unroll
        for (int j = 0; j < 8; ++j) {
            int gy = gy0 + j;
            bool ok = xok && gy >= 0 && gy < 512;
            size_t off = (size_t)gy * 512;
            av[j] = ok ? p1[off] : 0.f;       // exec-masked load, no fault
            bv[j] = ok ? p2[off] : 0.f;
        }
        // clip + 4 field planes, packed f32->f16 (OOB rows give eps~1e-6:
        // contribution ~1e-7 per tap, negligible -- R6-validated)
        H8 F0, F1, F2, F3;
        #pragma unroll
        for (int jj = 0; jj < 4; ++jj) {
            float a0 = fminf(fmaxf(av[2*jj],   eps), hiv);
            float a1 = fminf(fmaxf(av[2*jj+1], eps), hiv);
            float b0 = fminf(fmaxf(bv[2*jj],   eps), hiv);
            float b1 = fminf(fmaxf(bv[2*jj+1], eps), hiv);
            F0.p[jj] = __builtin_amdgcn_cvt_pkrtz(a0, a1);
            F1.p[jj] = __builtin_amdgcn_cvt_pkrtz(b0, b1);
            F2.p[jj] = __builtin_amdgcn_cvt_pkrtz(a0*a0 + b0*b0, a1*a1 + b1*b1);
            F3.p[jj] = __builtin_amdgcn_cvt_pkrtz(a0*b0, a1*b1);
        }
        accT[0] = __builtin_amdgcn_mfma_f32_32x32x16_f16(F0.v, band[ch], accT[0], 0, 0, 0);
        accT[1] = __builtin_amdgcn_mfma_f32_32x32x16_f16(F1.v, band[ch], accT[1], 0, 0, 0);
        accT[2] = __builtin_amdgcn_mfma_f32_32x32x16_f16(F2.v, band[ch], accT[2], 0, 0, 0);
        accT[3] = __builtin_amdgcn_mfma_f32_32x32x16_f16(F3.v, band[ch], accT[3], 0, 0, 0);
    }

    // ---- write T: D[m=pixel-col][n=T-row] -> lane ln owns T-row ln; regs
    // 4s..4s+3 are 4 CONSECUTIVE T-cols cb+8s..+3 -> 16 ds_write_b64 total ----
    {
        const int cb = 32 * wv + 4 * q;
        f16* trow = T + ln * TSTR + cb;
        #pragma unroll
        for (int f = 0; f < 4; ++f) {
            #pragma unroll
            for (int s = 0; s < 4; ++s) {
                H4 h;
                h.p[0] = __builtin_amdgcn_cvt_pkrtz(accT[f][4*s],   accT[f][4*s+1]);
                h.p[1] = __builtin_amdgcn_cvt_pkrtz(accT[f][4*s+2], accT[f][4*s+3]);
                *(half4*)(trow + f * T_FSZ + 8 * s) = h.v;
            }
        }
    }
    // zero T cols 128..143: H-pass A-frags read up to col 143 with zero band
    // weight, but 0 * garbage(inf/NaN) = NaN inside VALID outputs (R5 lesson).
    {
        int f = tid >> 6, row = (tid >> 1) & 31, seg = tid & 1;
        *(half8*)(T + f * T_FSZ + row * TSTR + 128 + seg * 8) = (half8)(f16)0.f;
    }
    __syncthreads();

    // ---- H-pass: OUT[r][32*wv+n] = sum_k g[k] T[r][32*wv+n+k] ----
    floatx16 accH[4] = {};
    #pragma unroll
    for (int ch = 0; ch < 3; ++ch) {
        const f16* tb = T + ln * TSTR + (32 * wv + 16 * ch + 8 * q);
        #pragma unroll
        for (int f = 0; f < 4; ++f) {
            half8 afrag = *(const half8*)(tb + f * T_FSZ);
            accH[f] = __builtin_amdgcn_mfma_f32_32x32x16_f16(afrag, band[ch], accH[f], 0, 0, 0);
        }
    }

    // ---- epilogue: ssim map + sum (cols masked to valid range) ----
    float vsum = 0.f;
    const int colL = 32 * wv + ln;
    if (colL < TILE_C && cx0 + colL < 512) {
        const float C1 = 1e-4f, C2 = 9e-4f;
        #pragma unroll
        for (int r = 0; r < 16; ++r) {
            float mu1 = accH[0][r], mu2 = accH[1][r];
            float S = accH[2][r], E12 = accH[3][r];
            float mu11 = mu1 * mu1, mu22 = mu2 * mu2, mu12 = mu1 * mu2;
            float num = (2.f * mu12 + C1) * (2.f * (E12 - mu12) + C2);
            float den = (mu11 + mu22 + C1) * (S - mu11 - mu22 + C2);
            vsum += num * __builtin_amdgcn_rcpf(den);   // 1-ulp rcp, den>=C1*C2
        }
    }

    // block reduction: wave shuffle -> LDS -> one fire-and-forget atomic
    #pragma unroll
    for (int off = 32; off > 0; off >>= 1) vsum += __shfl_down(vsum, off, 64);
    if ((tid & 63) == 0) wsum[tid >> 6] = vsum;
    __syncthreads();
    if (tid == 0) {
        atomicAdd(acc, wsum[0] + wsum[1] + wsum[2] + wsum[3]);
    }
}

__global__ void ssim_finalize(const float* __restrict__ acc,
                              float* __restrict__ out, float invN)
{
    out[0] = 1.0f - acc[0] * invN;
}

extern "C" void kernel_launch(void* const* d_in, const int* in_sizes, int n_in,
                              void* d_out, int out_size, void* d_ws, size_t ws_size,
                              hipStream_t stream) {
    const float* img1 = (const float*)d_in[0];
    const float* img2 = (const float*)d_in[1];
    const float* window = (const float*)d_in[2];
    float* out = (float*)d_out;
    float* acc = (float*)d_ws;

    const int B = 16, C = 3, H = 512, W = 512;
    const float invN = 1.0f / ((float)B * C * H * W);

    // d_ws is poisoned (0xAA) before every call: zero the accumulator
    hipMemsetAsync(acc, 0, sizeof(float), stream);

    dim3 block(256);
    dim3 grid((W + TILE_C - 1) / TILE_C, H / TILE_R, B * C);   // 5 x 16 x 48
    ssim_kernel<<<grid, block, 0, stream>>>(img1, img2, window, acc);
    ssim_finalize<<<1, 1, 0, stream>>>(acc, out, invN);
}

// Round 10
// 156.326 us; speedup vs baseline: 3.0494x; 1.1485x over previous
//
#include <hip/hip_runtime.h>

typedef _Float16 f16;
typedef __fp16 fp16x2 __attribute__((ext_vector_type(2)));
typedef _Float16 half4 __attribute__((ext_vector_type(4)));
typedef _Float16 half8 __attribute__((ext_vector_type(8)));
typedef float floatx16 __attribute__((ext_vector_type(16)));

#define KW 11
#define FSTR 48                        // r-dim per field in f16 (42 used, pad 48)
#define XSTR 200                       // per-x stride f16: 4*48 + 8 pad = 400 B
#define T_WAVE_BYTES (32 * XSTR * 2)   // 12800 B per wave

union H8 { half8 v; fp16x2 p[4]; };
union H4 { half4 v; fp16x2 p[2]; };

// Fused SSIM via MFMA, H-pass first:
//   pass1: T_h[r][x] = sum_k g[k-n-3] * X[row r][col x0-8+k]   (A = image fields,
//          rows in M/regs, x in N/lanes; A-frags = 2 aligned float4 global loads)
//   pass2: OUT^T[x][y] = sum_r g[r-y] * T_h[r][x]              (A = T_h^T from LDS b128)
// No per-element bounds masks: col chunks are uniformly in/out (x0-8 shift),
// row OOB handled by clamp + 0/1 mask multiply. Every T cell is written.
__global__ __launch_bounds__(256, 3) void ssim_kernel(
    const float* __restrict__ img1, const float* __restrict__ img2,
    const float* __restrict__ window, float* __restrict__ acc)
{
    __shared__ __align__(16) char smem[4 * T_WAVE_BYTES + 192 + 32];
    f16*   gpad = (f16*)(smem + 4 * T_WAVE_BYTES);   // 96 entries, g at [35..45]
    float* wsum = (float*)(smem + 4 * T_WAVE_BYTES + 192);

    const int tid  = threadIdx.x;
    const int lane = tid & 63;
    const int wv   = tid >> 6;        // wave -> x tile x0 = bx*128 + 32*wv
    const int q    = lane >> 5;
    const int ln   = lane & 31;

    const int bz = blockIdx.z;
    const int c  = bz % 3;
    const int x0 = blockIdx.x * 128 + 32 * wv;
    const int oy = blockIdx.y * 32;
    const size_t base = (size_t)bz * 512 * 512;

    f16* Tw = (f16*)(smem + wv * T_WAVE_BYTES);      // this wave's T^T [x32][f4][r48]

    // zero-padded 1-D gaussian: gpad[35+t] = g[t] = sum_j w2d[t][j]
    if (tid < 96) {
        float v = 0.f;
        if (tid >= 35 && tid < 35 + KW) {
            const float* w2 = window + c * KW * KW + (tid - 35) * KW;
            #pragma unroll
            for (int j = 0; j < KW; ++j) v += w2[j];
        }
        gpad[tid] = (f16)v;
    }
    __syncthreads();

    // band fragments, B[k=16ch+8q+j][n=ln]: band1 = g[k-n-3], band2 = g[k-n]
    half8 band1[3], band2[3];
    #pragma unroll
    for (int ch = 0; ch < 3; ++ch) {
        int d1 = 16 * ch + 8 * q - ln + 32;          // 35 - 3
        #pragma unroll
        for (int j = 0; j < 8; ++j) {
            band1[ch][j] = gpad[d1 + j];
            band2[ch][j] = gpad[d1 + 3 + j];
        }
    }

    const float eps = 1e-6f, hiv = 1.0f - 1e-6f;

    // ---- pass 1 (horizontal), two M-tiles of 32 rows ----
    #pragma unroll
    for (int m = 0; m < 2; ++m) {
        int row  = oy - 5 + ln + 32 * m;             // lane = A row
        int rowc = min(max(row, 0), 511);
        float rmask = (row == rowc) ? 1.f : 0.f;
        const float* r1 = img1 + base + (size_t)rowc * 512;
        const float* r2 = img2 + base + (size_t)rowc * 512;

        // 12 unconditional float4 loads (clamped base + mask), all in flight
        float4 ra[3][2], rb[3][2];
        float cmask[3];
        #pragma unroll
        for (int ch = 0; ch < 3; ++ch) {
            int cb  = x0 - 8 + 16 * ch + 8 * q;      // 8-col chunk, 32B aligned
            int cbc = min(max(cb, 0), 504);
            cmask[ch] = (cb == cbc) ? rmask : 0.f;   // chunk uniformly in/out
            ra[ch][0] = *(const float4*)(r1 + cbc);
            ra[ch][1] = *(const float4*)(r1 + cbc + 4);
            rb[ch][0] = *(const float4*)(r2 + cbc);
            rb[ch][1] = *(const float4*)(r2 + cbc + 4);
        }

        floatx16 accT[4] = {};
        #pragma unroll
        for (int ch = 0; ch < 3; ++ch) {
            float mk = cmask[ch];
            H8 F0, F1, F2, F3;
            #pragma unroll
            for (int h = 0; h < 2; ++h) {
                float as[4] = {ra[ch][h].x, ra[ch][h].y, ra[ch][h].z, ra[ch][h].w};
                float bs[4] = {rb[ch][h].x, rb[ch][h].y, rb[ch][h].z, rb[ch][h].w};
                #pragma unroll
                for (int t = 0; t < 2; ++t) {
                    float a0 = fminf(fmaxf(as[2*t],   eps), hiv) * mk;
                    float a1 = fminf(fmaxf(as[2*t+1], eps), hiv) * mk;
                    float b0 = fminf(fmaxf(bs[2*t],   eps), hiv) * mk;
                    float b1 = fminf(fmaxf(bs[2*t+1], eps), hiv) * mk;
                    int jj = 2 * h + t;
                    F0.p[jj] = __builtin_amdgcn_cvt_pkrtz(a0, a1);
                    F1.p[jj] = __builtin_amdgcn_cvt_pkrtz(b0, b1);
                    F2.p[jj] = __builtin_amdgcn_cvt_pkrtz(a0*a0 + b0*b0, a1*a1 + b1*b1);
                    F3.p[jj] = __builtin_amdgcn_cvt_pkrtz(a0*b0, a1*b1);
                }
            }
            accT[0] = __builtin_amdgcn_mfma_f32_32x32x16_f16(F0.v, band1[ch], accT[0], 0, 0, 0);
            accT[1] = __builtin_amdgcn_mfma_f32_32x32x16_f16(F1.v, band1[ch], accT[1], 0, 0, 0);
            accT[2] = __builtin_amdgcn_mfma_f32_32x32x16_f16(F2.v, band1[ch], accT[2], 0, 0, 0);
            accT[3] = __builtin_amdgcn_mfma_f32_32x32x16_f16(F3.v, band1[ch], accT[3], 0, 0, 0);
        }

        // write T^T: D[m=row r][n=x=ln]; reg quad s = 4 consecutive rows -> b64
        f16* tx = Tw + ln * XSTR;
        #pragma unroll
        for (int f = 0; f < 4; ++f) {
            #pragma unroll
            for (int s = 0; s < 4; ++s) {
                if (m == 1 && s >= 2) continue;      // rows 48..63 unused
                int r0 = 8 * s + 4 * q + 32 * m;
                H4 h4;
                h4.p[0] = __builtin_amdgcn_cvt_pkrtz(accT[f][4*s],   accT[f][4*s+1]);
                h4.p[1] = __builtin_amdgcn_cvt_pkrtz(accT[f][4*s+2], accT[f][4*s+3]);
                *(half4*)(tx + f * FSTR + r0) = h4.v;
            }
        }
    }
    __syncthreads();

    // ---- pass 2 (vertical): OUT^T = T_h^T * band2; A-frags = b128 LDS reads ----
    floatx16 accH[4] = {};
    #pragma unroll
    for (int ch = 0; ch < 3; ++ch) {
        const f16* tb = Tw + ln * XSTR + 16 * ch + 8 * q;
        #pragma unroll
        for (int f = 0; f < 4; ++f) {
            half8 af = *(const half8*)(tb + f * FSTR);
            accH[f] = __builtin_amdgcn_mfma_f32_32x32x16_f16(af, band2[ch], accH[f], 0, 0, 0);
        }
    }

    // ---- epilogue: all 16 outputs per lane are valid (exact tiling) ----
    float vsum = 0.f;
    const float C1 = 1e-4f, C2 = 9e-4f;
    #pragma unroll
    for (int r = 0; r < 16; ++r) {
        float mu1 = accH[0][r], mu2 = accH[1][r];
        float S = accH[2][r], E12 = accH[3][r];
        float mu11 = mu1 * mu1, mu22 = mu2 * mu2, mu12 = mu1 * mu2;
        float num = (2.f * mu12 + C1) * (2.f * (E12 - mu12) + C2);
        float den = (mu11 + mu22 + C1) * (S - mu11 - mu22 + C2);
        vsum += num * __builtin_amdgcn_rcpf(den);
    }

    // block reduction: wave shuffle -> LDS -> one fire-and-forget atomic
    #pragma unroll
    for (int off = 32; off > 0; off >>= 1) vsum += __shfl_down(vsum, off, 64);
    if ((tid & 63) == 0) wsum[tid >> 6] = vsum;
    __syncthreads();
    if (tid == 0) {
        atomicAdd(acc, wsum[0] + wsum[1] + wsum[2] + wsum[3]);
    }
}

__global__ void ssim_finalize(const float* __restrict__ acc,
                              float* __restrict__ out, float invN)
{
    out[0] = 1.0f - acc[0] * invN;
}

extern "C" void kernel_launch(void* const* d_in, const int* in_sizes, int n_in,
                              void* d_out, int out_size, void* d_ws, size_t ws_size,
                              hipStream_t stream) {
    const float* img1 = (const float*)d_in[0];
    const float* img2 = (const float*)d_in[1];
    const float* window = (const float*)d_in[2];
    float* out = (float*)d_out;
    float* acc = (float*)d_ws;

    const int B = 16, C = 3, H = 512, W = 512;
    const float invN = 1.0f / ((float)B * C * H * W);

    // d_ws is poisoned (0xAA) before every call: zero the accumulator
    hipMemsetAsync(acc, 0, sizeof(float), stream);

    dim3 block(256);
    dim3 grid(W / 128, H / 32, B * C);   // 4 x 16 x 48 = 3072 blocks
    ssim_kernel<<<grid, block, 0, stream>>>(img1, img2, window, acc);
    ssim_finalize<<<1, 1, 0, stream>>>(acc, out, invN);
}